// Round 4
// baseline (487.837 us; speedup 1.0000x reference)
//
#include <hip/hip_runtime.h>
#include <hip/hip_bf16.h>
#include <cstdint>

typedef __attribute__((ext_vector_type(8))) _Float16 f16x8;
typedef __attribute__((ext_vector_type(4))) _Float16 f16x4;
typedef __attribute__((ext_vector_type(4))) float f32x4;

#define GOLDEN_CENTER_F 0.36787944117144233f
#define GOLDEN_LOWER_F  0.21231792754821915f
#define GOLDEN_UPPER_F  0.5f

static constexpr int Dm = 1024;
static constexpr int Im = 1024;
static constexpr int NTOK = 8192;
static constexpr int NE = 8;

__device__ __forceinline__ void async16(const _Float16* g, _Float16* l) {
  __builtin_amdgcn_global_load_lds(
      (const __attribute__((address_space(1))) void*)g,
      (__attribute__((address_space(3))) void*)l,
      16, 0, 0);
}

// ---------------- routing (exact fp32) + fused x->fp16 conversion ----------------
__global__ void routing_kernel(const float* __restrict__ x, const float* __restrict__ Wr,
                               const float* __restrict__ temp, float* __restrict__ wts,
                               _Float16* __restrict__ xb) {
  const int wave = threadIdx.x >> 6, lane = threadIdx.x & 63;
  const int t = blockIdx.x * 4 + wave;
  const float* xr = x + (size_t)t * Dm;
  _Float16* xo = xb + (size_t)t * Dm;
  float acc[NE] = {0.f,0.f,0.f,0.f,0.f,0.f,0.f,0.f};
  const int d0 = lane * 16;
#pragma unroll
  for (int j = 0; j < 4; ++j) {
    float4 v = *(const float4*)(xr + d0 + j * 4);
    f16x4 h = {(_Float16)v.x, (_Float16)v.y, (_Float16)v.z, (_Float16)v.w};
    *(f16x4*)(xo + d0 + j * 4) = h;
    const float* wr = Wr + (size_t)(d0 + j * 4) * NE;
#pragma unroll
    for (int e = 0; e < NE; ++e)
      acc[e] += v.x * wr[e] + v.y * wr[NE + e] + v.z * wr[2 * NE + e] + v.w * wr[3 * NE + e];
  }
#pragma unroll
  for (int off = 32; off > 0; off >>= 1) {
#pragma unroll
    for (int e = 0; e < NE; ++e) acc[e] += __shfl_down(acc[e], off, 64);
  }
  if (lane == 0) {
    float T = temp[0];
    float w[NE], dist[NE];
    float wsum = 0.f;
#pragma unroll
    for (int e = 0; e < NE; ++e) {
      float inh = 1.f / (1.f + expf(-acc[e] / T));
      dist[e] = fabsf(inh - GOLDEN_CENTER_F);
      bool zone = (inh >= GOLDEN_LOWER_F) && (inh <= GOLDEN_UPPER_F);
      w[e] = zone ? expf(-dist[e] / 0.1f) : 0.f;
      wsum += w[e];
    }
    if (wsum < 1e-8f) {
      float fb[NE];
#pragma unroll
      for (int e = 0; e < NE; ++e) fb[e] = expf(-dist[e] / 0.3f);
      int i1 = 0;
      for (int e = 1; e < NE; ++e) if (fb[e] > fb[i1]) i1 = e;
      int i2 = (i1 == 0) ? 1 : 0;
      for (int e = 0; e < NE; ++e) if (e != i1 && fb[e] > fb[i2]) i2 = e;
      float s = fmaxf(fb[i1] + fb[i2], 1e-8f);
#pragma unroll
      for (int e = 0; e < NE; ++e) w[e] = 0.f;
      w[i1] = fb[i1] / s;
      w[i2] = fb[i2] / s;
      wsum = w[i1] + w[i2];
    }
    float inv = 1.f / fmaxf(wsum, 1e-8f);
#pragma unroll
    for (int e = 0; e < NE; ++e) wts[(size_t)t * NE + e] = w[e] * inv;
  }
}

// ---------------- compaction: per-expert active-token lists + pos table ----------------
__global__ void compact_kernel(const float* __restrict__ wts, int* __restrict__ tok,
                               float* __restrict__ wc, int* __restrict__ cnt,
                               int* __restrict__ pos) {
  const int e = blockIdx.x;
  const int tid = threadIdx.x;
  const int wave = tid >> 6, lane = tid & 63;
  __shared__ int wcnt[4];
  __shared__ int s_running;
  if (tid == 0) s_running = 0;
  __syncthreads();
  for (int base = 0; base < NTOK; base += 256) {
    int t = base + tid;
    float w = wts[(size_t)t * NE + e];
    bool act = w > 0.f;
    unsigned long long mask = __ballot(act);
    int prefix = __popcll(mask & ((1ull << lane) - 1ull));
    if (lane == 0) wcnt[wave] = __popcll(mask);
    __syncthreads();
    int wbase = 0;
    for (int i = 0; i < wave; ++i) wbase += wcnt[i];
    int run = s_running;
    int p = run + wbase + prefix;
    pos[(size_t)t * NE + e] = act ? p : -1;
    if (act) {
      tok[(size_t)e * NTOK + p] = t;
      wc[(size_t)e * NTOK + p] = w;
    }
    __syncthreads();
    if (tid == 0) s_running = run + wcnt[0] + wcnt[1] + wcnt[2] + wcnt[3];
    __syncthreads();
  }
  int c = s_running;
  if (tid == 0) cnt[e] = c;
  int padded = (c + 127) & ~127;
  for (int p = c + tid; p < padded; p += 256) {
    tok[(size_t)e * NTOK + p] = 0;
    wc[(size_t)e * NTOK + p] = 0.f;
  }
}

// ---------------- transpose+convert: Wg/Wu interleaved into Wgu (16-col blocks), Wd -> WdT --------
// Wgu[e][n][k]: n = 32*(c>>4) + (c&15)      for gate col c
//              n = 32*(c>>4) + 16 + (c&15)  for up   col c
// (verified correct in Round 2)
__global__ void transpose_cvt_kernel(const float* __restrict__ Wg, const float* __restrict__ Wu,
                                     const float* __restrict__ Wd, _Float16* __restrict__ Wgu,
                                     _Float16* __restrict__ WdT) {
  __shared__ float tile[32][33];
  const int which = blockIdx.z >> 3;
  const int e = blockIdx.z & 7;
  const float* src = which == 0 ? Wg : which == 1 ? Wu : Wd;
  const size_t sbase = (size_t)e * 1024 * 1024;
  const int r0 = blockIdx.y * 32, c0 = blockIdx.x * 32;
  const int tx = threadIdx.x & 31, ty = threadIdx.x >> 5;
#pragma unroll
  for (int j = 0; j < 32; j += 8)
    tile[ty + j][tx] = src[sbase + (size_t)(r0 + ty + j) * 1024 + c0 + tx];
  __syncthreads();
#pragma unroll
  for (int j = 0; j < 32; j += 8) {
    const int c = c0 + ty + j;
    float v = tile[tx][ty + j];
    if (which == 2) {
      WdT[sbase + (size_t)c * 1024 + r0 + tx] = (_Float16)v;
    } else {
      const int n = ((c >> 4) << 5) + (which << 4) + (c & 15);
      Wgu[(size_t)e * 2048 * 1024 + (size_t)n * 1024 + r0 + tx] = (_Float16)v;
    }
  }
}

// ================= 128x128xBK64 counted-vmcnt double-buffered GEMMs =================
// 4 waves (2M x 2N), per-wave C = 64x64 (acc[4][4]).
// LDS: [2 buf][128 rows][64 k] per operand = 32KB each, 64KB total -> 2 blocks/CU.
// Pipeline: at top of tile t, stage tile t+1 (8 async16/thread), then
//   s_waitcnt vmcnt(8)  -> tile t's 8 loads (issued one FULL K-tile earlier) done;
//   trailing barrier carries only lgkmcnt(0) -- NO vmcnt(0) drain in the main loop.
// Swizzle (both-sides involution, BK=64 variant): LDS 16B-chunk c of row r holds
//   logical k-chunk c ^ (r&7); staged by inverse-permuting the global source chunk.
//   Reads: 8 lanes per 16B slot-column, uniform (same class as R1's measured-zero pattern).

// ---------------- gemm1: h = silu(x@Wg)*(x@Wu), combined-B (Wgu), gathered rows ----------------
__global__ __launch_bounds__(256, 2) void gemm1_kernel(
    const _Float16* __restrict__ A, const _Float16* __restrict__ Bgu,
    const int* __restrict__ tok, const int* __restrict__ cnt,
    _Float16* __restrict__ hbuf, int ebase) {
  constexpr int K = Dm, NT = K / 64;
  const int z = blockIdx.z;
  const int e = ebase + z;
  const int r0 = blockIdx.x * 128;      // row-block fastest (L2 B-tile reuse)
  if (r0 >= cnt[e]) return;
  const int n0 = blockIdx.y * 128;      // combined-col base (0..2047)
  const _Float16* Bm = Bgu + (size_t)e * 2048 * Dm;
  _Float16* H = hbuf + (size_t)z * NTOK * Im;
  const int* tk = tok + (size_t)e * NTOK;

  __shared__ _Float16 sA[2][8192];
  __shared__ _Float16 sB[2][8192];
  const int tid = threadIdx.x, lane = tid & 63, w = tid >> 6;
  const int m_off = (w & 1) * 64, n_off = (w >> 1) * 64;

  // staging: slot s = j*256+tid -> row s>>3 (= j*32 + (tid>>3)), phys chunk s&7 (= tid&7)
  // source logical chunk = (tid&7) ^ (row&7), row&7 = (tid>>3)&7
  const int lcc = (tid & 7) ^ ((tid >> 3) & 7);
  const _Float16* pA[4];
  const _Float16* pB[4];
#pragma unroll
  for (int j = 0; j < 4; ++j) {
    pA[j] = A + (size_t)tk[r0 + j * 32 + (tid >> 3)] * K + lcc * 8;
    pB[j] = Bm + (size_t)(n0 + j * 32 + (tid >> 3)) * K + lcc * 8;
  }

  auto STAGE = [&](int b, int ko) {
#pragma unroll
    for (int j = 0; j < 4; ++j) async16(pA[j] + ko, &sA[b][(j * 256 + tid) * 8]);
#pragma unroll
    for (int j = 0; j < 4; ++j) async16(pB[j] + ko, &sB[b][(j * 256 + tid) * 8]);
  };

  // read side: elem off = (m_off + i*16 + fr)*64 + ((kk*4+fq)^(fr&7))*8
  const int fr = lane & 15, fq = lane >> 4;
  const int axr = (m_off + fr) * 64;
  const int bxr = (n_off + fr) * 64;
  const int c0 = (fq ^ (fr & 7)) * 8;
  const int c1 = ((4 + fq) ^ (fr & 7)) * 8;

  f32x4 acc[4][4];
#pragma unroll
  for (int i = 0; i < 4; ++i)
#pragma unroll
    for (int j = 0; j < 4; ++j) acc[i][j] = (f32x4)0.f;

  STAGE(0, 0);
  for (int t = 0; t < NT; ++t) {
    const int p = t & 1;
    if (t + 1 < NT) {
      STAGE(p ^ 1, (t + 1) * 64);
      asm volatile("s_waitcnt vmcnt(8)\n\ts_barrier" ::: "memory");
    } else {
      asm volatile("s_waitcnt vmcnt(0)\n\ts_barrier" ::: "memory");
    }
    const _Float16* Ab = sA[p];
    const _Float16* Bb = sB[p];
    f16x8 af[4], bf[4];
    // k-slice 0
#pragma unroll
    for (int i = 0; i < 4; ++i) af[i] = *(const f16x8*)(Ab + axr + i * 1024 + c0);
#pragma unroll
    for (int i = 0; i < 4; ++i) bf[i] = *(const f16x8*)(Bb + bxr + i * 1024 + c0);
#pragma unroll
    for (int im = 0; im < 4; ++im)
#pragma unroll
      for (int in = 0; in < 4; ++in)
        acc[im][in] = __builtin_amdgcn_mfma_f32_16x16x32_f16(af[im], bf[in], acc[im][in], 0, 0, 0);
    // k-slice 1
#pragma unroll
    for (int i = 0; i < 4; ++i) af[i] = *(const f16x8*)(Ab + axr + i * 1024 + c1);
#pragma unroll
    for (int i = 0; i < 4; ++i) bf[i] = *(const f16x8*)(Bb + bxr + i * 1024 + c1);
#pragma unroll
    for (int im = 0; im < 4; ++im)
#pragma unroll
      for (int in = 0; in < 4; ++in)
        acc[im][in] = __builtin_amdgcn_mfma_f32_16x16x32_f16(af[im], bf[in], acc[im][in], 0, 0, 0);
    // protect buf p: all ds_reads done before anyone stages into it next iteration
    asm volatile("s_waitcnt lgkmcnt(0)\n\ts_barrier" ::: "memory");
  }

  // epilogue: acc[im][2q]=gate, acc[im][2q+1]=up for the same h-cols
  const int hc0 = ((n0 + n_off) >> 1) + fr;
#pragma unroll
  for (int im = 0; im < 4; ++im) {
    const int rowb = r0 + m_off + im * 16 + fq * 4;
#pragma unroll
    for (int q = 0; q < 2; ++q) {
      const int hcol = hc0 + q * 16;
#pragma unroll
      for (int r = 0; r < 4; ++r) {
        float g = acc[im][2 * q][r], u = acc[im][2 * q + 1][r];
        float s = g / (1.f + __expf(-g));
        H[(size_t)(rowb + r) * Im + hcol] = (_Float16)(s * u);
      }
    }
  }
}

// ---------------- gemm2: ebuf = h @ Wd  (same pipeline, direct rows) ----------------
__global__ __launch_bounds__(256, 2) void gemm2_kernel(
    const _Float16* __restrict__ hb, const _Float16* __restrict__ BAll,
    const int* __restrict__ cnt, _Float16* __restrict__ ebuf, int ebase) {
  constexpr int K = Im, NT = K / 64;
  const int z = blockIdx.z;
  const int e = ebase + z;
  const int r0 = blockIdx.x * 128;
  if (r0 >= cnt[e]) return;
  const int n0 = blockIdx.y * 128;
  const _Float16* A = hb + (size_t)z * NTOK * Im;
  const _Float16* Bm = BAll + (size_t)e * Im * Dm;
  _Float16* Ez = ebuf + (size_t)z * NTOK * Dm;

  __shared__ _Float16 sA[2][8192];
  __shared__ _Float16 sB[2][8192];
  const int tid = threadIdx.x, lane = tid & 63, w = tid >> 6;
  const int m_off = (w & 1) * 64, n_off = (w >> 1) * 64;

  const int lcc = (tid & 7) ^ ((tid >> 3) & 7);
  const _Float16* pA[4];
  const _Float16* pB[4];
#pragma unroll
  for (int j = 0; j < 4; ++j) {
    pA[j] = A + (size_t)(r0 + j * 32 + (tid >> 3)) * K + lcc * 8;
    pB[j] = Bm + (size_t)(n0 + j * 32 + (tid >> 3)) * K + lcc * 8;
  }

  auto STAGE = [&](int b, int ko) {
#pragma unroll
    for (int j = 0; j < 4; ++j) async16(pA[j] + ko, &sA[b][(j * 256 + tid) * 8]);
#pragma unroll
    for (int j = 0; j < 4; ++j) async16(pB[j] + ko, &sB[b][(j * 256 + tid) * 8]);
  };

  const int fr = lane & 15, fq = lane >> 4;
  const int axr = (m_off + fr) * 64;
  const int bxr = (n_off + fr) * 64;
  const int c0 = (fq ^ (fr & 7)) * 8;
  const int c1 = ((4 + fq) ^ (fr & 7)) * 8;

  f32x4 acc[4][4];
#pragma unroll
  for (int i = 0; i < 4; ++i)
#pragma unroll
    for (int j = 0; j < 4; ++j) acc[i][j] = (f32x4)0.f;

  STAGE(0, 0);
  for (int t = 0; t < NT; ++t) {
    const int p = t & 1;
    if (t + 1 < NT) {
      STAGE(p ^ 1, (t + 1) * 64);
      asm volatile("s_waitcnt vmcnt(8)\n\ts_barrier" ::: "memory");
    } else {
      asm volatile("s_waitcnt vmcnt(0)\n\ts_barrier" ::: "memory");
    }
    const _Float16* Ab = sA[p];
    const _Float16* Bb = sB[p];
    f16x8 af[4], bf[4];
#pragma unroll
    for (int i = 0; i < 4; ++i) af[i] = *(const f16x8*)(Ab + axr + i * 1024 + c0);
#pragma unroll
    for (int i = 0; i < 4; ++i) bf[i] = *(const f16x8*)(Bb + bxr + i * 1024 + c0);
#pragma unroll
    for (int im = 0; im < 4; ++im)
#pragma unroll
      for (int in = 0; in < 4; ++in)
        acc[im][in] = __builtin_amdgcn_mfma_f32_16x16x32_f16(af[im], bf[in], acc[im][in], 0, 0, 0);
#pragma unroll
    for (int i = 0; i < 4; ++i) af[i] = *(const f16x8*)(Ab + axr + i * 1024 + c1);
#pragma unroll
    for (int i = 0; i < 4; ++i) bf[i] = *(const f16x8*)(Bb + bxr + i * 1024 + c1);
#pragma unroll
    for (int im = 0; im < 4; ++im)
#pragma unroll
      for (int in = 0; in < 4; ++in)
        acc[im][in] = __builtin_amdgcn_mfma_f32_16x16x32_f16(af[im], bf[in], acc[im][in], 0, 0, 0);
    asm volatile("s_waitcnt lgkmcnt(0)\n\ts_barrier" ::: "memory");
  }

#pragma unroll
  for (int im = 0; im < 4; ++im) {
    const int rowb = r0 + m_off + im * 16 + fq * 4;
#pragma unroll
    for (int in = 0; in < 4; ++in) {
      const int col = n0 + n_off + in * 16 + fr;
#pragma unroll
      for (int r = 0; r < 4; ++r)
        Ez[(size_t)(rowb + r) * Dm + col] = (_Float16)acc[im][in][r];
    }
  }
}

// ---------------- combine: out[t] (=/+=) sum_{j<g} w[t,ebase+j] * ebuf[j][pos(t,ebase+j)] ----------------
__global__ void combine_kernel(const _Float16* __restrict__ ebuf, const int* __restrict__ pos,
                               const float* __restrict__ wts, float* __restrict__ out,
                               int ebase, int g, int accum) {
  const int t = blockIdx.x;
  __shared__ int sp[NE];
  __shared__ float swt[NE];
  if (threadIdx.x < g) {
    sp[threadIdx.x] = pos[(size_t)t * NE + ebase + threadIdx.x];
    swt[threadIdx.x] = wts[(size_t)t * NE + ebase + threadIdx.x];
  }
  __syncthreads();
  const int c = threadIdx.x * 4;
  float4 s;
  if (accum) s = *(const float4*)(out + (size_t)t * Dm + c);
  else s = float4{0.f, 0.f, 0.f, 0.f};
  for (int j = 0; j < g; ++j) {
    int p = sp[j];
    if (p >= 0) {
      float w = swt[j];
      f16x4 v = *(const f16x4*)(ebuf + ((size_t)j * NTOK + p) * Dm + c);
      s.x += w * (float)v[0];
      s.y += w * (float)v[1];
      s.z += w * (float)v[2];
      s.w += w * (float)v[3];
    }
  }
  *(float4*)(out + (size_t)t * Dm + c) = s;
}

// ---------------- launch ----------------
extern "C" void kernel_launch(void* const* d_in, const int* in_sizes, int n_in,
                              void* d_out, int out_size, void* d_ws, size_t ws_size,
                              hipStream_t stream) {
  const float* x    = (const float*)d_in[0];
  const float* Wg   = (const float*)d_in[1];
  const float* Wu   = (const float*)d_in[2];
  const float* Wd   = (const float*)d_in[3];
  const float* Wr   = (const float*)d_in[4];
  const float* temp = (const float*)d_in[5];
  float* out = (float*)d_out;

  char* ws = (char*)d_ws;
  size_t off = 0;
  auto carve = [&](size_t bytes) {
    char* p = ws + off;
    off = (off + bytes + 255) & ~(size_t)255;
    return p;
  };
  float* wts = (float*)carve((size_t)NTOK * NE * 4);
  int*   tok = (int*)  carve((size_t)NE * NTOK * 4);
  float* wc  = (float*)carve((size_t)NE * NTOK * 4);
  int*   pos = (int*)  carve((size_t)NTOK * NE * 4);
  int*   cnt = (int*)  carve(4096);
  _Float16* xb   = (_Float16*)carve((size_t)NTOK * Dm * 2);
  _Float16* Wgu  = (_Float16*)carve((size_t)NE * 2048 * Dm * 2);
  _Float16* WdT  = (_Float16*)carve((size_t)NE * Im * Dm * 2);
  const size_t fixed_off = off;
  const size_t per_expert = (size_t)NTOK * Im * 2 + (size_t)NTOK * Dm * 2; // hbuf+ebuf per expert
  int g = (ws_size >= fixed_off + 8 * per_expert) ? 8 : 4;
  _Float16* hbuf = (_Float16*)carve((size_t)g * NTOK * Im * 2);
  _Float16* ebuf = (_Float16*)carve((size_t)g * NTOK * Dm * 2);

  routing_kernel<<<NTOK / 4, 256, 0, stream>>>(x, Wr, temp, wts, xb);
  compact_kernel<<<NE, 256, 0, stream>>>(wts, tok, wc, cnt, pos);
  transpose_cvt_kernel<<<dim3(32, 32, 24), 256, 0, stream>>>(Wg, Wu, Wd, Wgu, WdT);

  for (int e0 = 0; e0 < NE; e0 += g) {
    // x = row-blocks (fastest) so the B col-tile stays L2-resident across the row sweep
    gemm1_kernel<<<dim3(NTOK / 128, 2048 / 128, g), 256, 0, stream>>>(xb, Wgu, tok, cnt, hbuf, e0);
    gemm2_kernel<<<dim3(NTOK / 128, Dm / 128, g), 256, 0, stream>>>(hbuf, WdT, cnt, ebuf, e0);
    combine_kernel<<<NTOK, 256, 0, stream>>>(ebuf, pos, wts, out, e0, g, e0 > 0);
  }
}